// Round 11
// baseline (830.906 us; speedup 1.0000x reference)
//
#include <hip/hip_runtime.h>
#include <hip/hip_bf16.h>

// ---------------- workspace layout (float offsets, fixed small region) ----------------
#define OFF_WN   0
#define OFF_BN   1024
#define OFF_WE   1088
#define OFF_BE   1600
#define OFF_WM   1664            // 3 * 128 * 64
#define OFF_BM   26240           // 3 * 64
#define OFF_WU   26432           // 3 * 128 * 64
#define OFF_BU   51008           // 3 * 64
#define OFF_WS1  51200           // 128 * 64
#define OFF_BS1  59392
#define OFF_WS2  59456
#define OFF_BS2  59520
#define OFF_WK1  59521           // 68 * 32
#define OFF_BK1  61697
#define OFF_WK2  61729           // 32 * 16
#define OFF_BK2  62241
#define OFF_WK3  62257
#define OFF_BK3  62273
#define OFF_TS   62274           // traffic stats (4)
#define OFF_GSUM 62278           // graph-embed accumulator (64)
#define OFF_FLAG 62344           // dtype flag: 1 = inputs are f32, 0 = bf16
#define OFF_BSUM 62400           // block sums for scan (<=400)
#define OFF_BOFF 62900           // block offsets for scan (<=400)
#define OFF_H    65536           // big arrays start here (see kernel_launch)

typedef __attribute__((ext_vector_type(8))) short bfrag;   // 8 bf16 (4 VGPRs)
typedef __attribute__((ext_vector_type(4))) float ffrag;   // 4 f32 acc

__device__ __forceinline__ float bf2f(unsigned short u) {
    unsigned int i = ((unsigned int)u) << 16;
    float f;
    __builtin_memcpy(&f, &i, sizeof(f));
    return f;
}
__device__ __forceinline__ float bflo(unsigned int u) {
    unsigned int i = u << 16;
    float f; __builtin_memcpy(&f, &i, sizeof(f)); return f;
}
__device__ __forceinline__ float bfhi(unsigned int u) {
    unsigned int i = u & 0xffff0000u;
    float f; __builtin_memcpy(&f, &i, sizeof(f)); return f;
}
__device__ __forceinline__ unsigned int f2bf_rne(float f) {
    unsigned int u; __builtin_memcpy(&u, &f, 4);
    return (u + 0x7fffu + ((u >> 16) & 1u)) >> 16;
}
__device__ __forceinline__ unsigned int pack2bf(float a, float b) {
    return f2bf_rne(a) | (f2bf_rne(b) << 16);
}

// ---------------- dtype sniffer (R2 evidence: takes the f32 branch) ----------------
__global__ void detect_dtype_kernel(const unsigned short* __restrict__ nf,
                                    int* __restrict__ flag) {
    int t = threadIdx.x;  // 64 threads
    float m = 0.f;
    for (int i = t; i < 1024; i += 64) {
        float v = fabsf(bf2f(nf[i]));
        if (!isnan(v)) m = fmaxf(m, v);
        else m = 1e30f;
    }
    for (int o = 32; o > 0; o >>= 1) m = fmaxf(m, __shfl_down(m, o));
    if (t == 0) flag[0] = (m > 1e6f) ? 1 : 0;
}

// ---------------- weight conversion ----------------
struct ConvArgs {
    const void* src[19];
    int off[19];
    int n[19];
};

__global__ __launch_bounds__(256) void convert_all_kernel(
        ConvArgs a, float* __restrict__ ws, const int* __restrict__ flagp) {
    int isf32 = *flagp;
    int ai = blockIdx.y;
    int i  = blockIdx.x * blockDim.x + threadIdx.x;
    if (i < a.n[ai]) {
        float v = isf32 ? ((const float*)a.src[ai])[i]
                        : bf2f(((const unsigned short*)a.src[ai])[i]);
        ws[a.off[ai] + i] = v;
    }
}

// ---------------- transposed bf16 weight prep ----------------
// WbT[l][n*64+k]  = Wm2[l][k][n]         (12288 shorts)
// W1T[l][n*64+k]  = Wm1[l][k][n]         (12288 shorts)
// WuT[l][n*128+k] = Wu[l][k][n]          (24576 shorts)
// WeT[n*32+k]     = k<8 ? We[k][n] : 0   (2048 shorts, zero-padded K)
__global__ __launch_bounds__(256) void wtrans_prep_kernel(
        const float* __restrict__ ws, short* __restrict__ Wb) {
    int idx = blockIdx.x * 256 + threadIdx.x;
    if (idx < 12288) {
        int l = idx >> 12, rem = idx & 4095, n = rem >> 6, k = rem & 63;
        Wb[idx] = (short)f2bf_rne(ws[OFF_WM + l * 8192 + 4096 + k * 64 + n]);
    } else if (idx < 24576) {
        int j = idx - 12288;
        int l = j >> 12, rem = j & 4095, n = rem >> 6, k = rem & 63;
        Wb[idx] = (short)f2bf_rne(ws[OFF_WM + l * 8192 + k * 64 + n]);
    } else if (idx < 49152) {
        int j = idx - 24576;
        int l = j >> 13, rem = j & 8191, n = rem >> 7, k = rem & 127;
        Wb[idx] = (short)f2bf_rne(ws[OFF_WU + l * 8192 + k * 64 + n]);
    } else if (idx < 51200) {
        int j = idx - 49152;
        int n = j >> 5, k = j & 31;
        Wb[idx] = (k < 8) ? (short)f2bf_rne(ws[OFF_WE + k * 64 + n]) : (short)0;
    }
}

// ---------------- node projection: h = relu(nf @ Wn + bn) ----------------
__global__ __launch_bounds__(256) void node_proj_kernel(
        const void* __restrict__ nf, const float* __restrict__ ws,
        float* __restrict__ h, int N, const int* __restrict__ flagp) {
    int idx = blockIdx.x * blockDim.x + threadIdx.x;
    if (idx >= N * 64) return;
    int isf32 = *flagp;
    int i = idx >> 6, c = idx & 63;
    const float* Wn = ws + OFF_WN;
    float acc = ws[OFF_BN + c];
    float x[16];
    if (isf32) {
        const float* row = (const float*)nf + (size_t)i * 16;
#pragma unroll
        for (int k = 0; k < 16; ++k) x[k] = row[k];
    } else {
        const unsigned short* row = (const unsigned short*)nf + (size_t)i * 16;
#pragma unroll
        for (int k = 0; k < 16; ++k) x[k] = bf2f(row[k]);
    }
#pragma unroll
    for (int k = 0; k < 16; ++k) acc = fmaf(x[k], Wn[k * 64 + c], acc);
    h[idx] = fmaxf(acc, 0.f);
}

// ---------------- CSR build ----------------
__global__ __launch_bounds__(256) void count_kernel(
        const int* __restrict__ dst, int* __restrict__ deg, int E) {
    int e = blockIdx.x * blockDim.x + threadIdx.x;
    if (e < E) atomicAdd(&deg[dst[e]], 1);
}

__global__ __launch_bounds__(256) void scan_blocks_kernel(
        const int* __restrict__ deg, int* __restrict__ incl,
        int* __restrict__ bsum, int N) {
    int tid = threadIdx.x;
    int gid = blockIdx.x * 256 + tid;
    int v = (gid < N) ? deg[gid] : 0;
    int lane = tid & 63, w = tid >> 6;
    int x = v;
#pragma unroll
    for (int o = 1; o < 64; o <<= 1) {
        int y = __shfl_up(x, o);
        if (lane >= o) x += y;
    }
    __shared__ int wsum[4];
    __shared__ int woff[4];
    if (lane == 63) wsum[w] = x;
    __syncthreads();
    if (tid == 0) {
        int a = 0;
#pragma unroll
        for (int i = 0; i < 4; ++i) { woff[i] = a; a += wsum[i]; }
    }
    __syncthreads();
    x += woff[w];
    if (gid < N) incl[gid] = x;
    if (tid == 255) bsum[blockIdx.x] = x;
}

__global__ __launch_bounds__(256) void scan_bsum_kernel(
        const int* __restrict__ bsum, int* __restrict__ boff, int nb) {
    __shared__ int sh[256];
    int tid = threadIdx.x;
    int carry = 0;
    for (int base = 0; base < nb; base += 256) {
        int v = (base + tid < nb) ? bsum[base + tid] : 0;
        sh[tid] = v;
        __syncthreads();
        for (int o = 1; o < 256; o <<= 1) {
            int t = (tid >= o) ? sh[tid - o] : 0;
            __syncthreads();
            sh[tid] += t;
            __syncthreads();
        }
        if (base + tid < nb) boff[base + tid] = carry + sh[tid] - v;
        __syncthreads();
        carry += sh[255];
        __syncthreads();
    }
}

__global__ __launch_bounds__(256) void scan_finalize_kernel(
        const int* __restrict__ deg, const int* __restrict__ incl,
        const int* __restrict__ boff, int* __restrict__ out,
        int* __restrict__ cursor, int N, int tailval) {
    int gid = blockIdx.x * 256 + threadIdx.x;
    if (gid < N) {
        int ex = boff[blockIdx.x] + incl[gid] - deg[gid];
        out[gid] = ex;
        cursor[gid] = ex;
    }
    if (gid == 0) out[N] = tailval;
}

// fill CSR. big mode: one 64-B record {src,dst,ef[8],pad} per slot.
__global__ __launch_bounds__(256) void fill_kernel(
        const int* __restrict__ src, const int* __restrict__ dst,
        const void* __restrict__ ef, int* __restrict__ cursor,
        int* __restrict__ eid, int* __restrict__ srcs,
        float* __restrict__ rec, int E, int big,
        const int* __restrict__ flagp) {
    int e = blockIdx.x * blockDim.x + threadIdx.x;
    if (e >= E) return;
    int d = dst[e];
    int pos = atomicAdd(&cursor[d], 1);
    if (big) {
        float v[8];
        if (*flagp) {
            const float4* p = (const float4*)ef + (size_t)e * 2;
            float4 a = p[0], b = p[1];
            v[0]=a.x; v[1]=a.y; v[2]=a.z; v[3]=a.w;
            v[4]=b.x; v[5]=b.y; v[6]=b.z; v[7]=b.w;
        } else {
            uint4 r = ((const uint4*)ef)[e];
            v[0]=bflo(r.x); v[1]=bfhi(r.x); v[2]=bflo(r.y); v[3]=bfhi(r.y);
            v[4]=bflo(r.z); v[5]=bfhi(r.z); v[6]=bflo(r.w); v[7]=bfhi(r.w);
        }
        float4* o = (float4*)(rec + (size_t)pos * 16);
        o[0] = make_float4(__int_as_float(src[e]), __int_as_float(d), v[0], v[1]);
        o[1] = make_float4(v[2], v[3], v[4], v[5]);
        o[2] = make_float4(v[6], v[7], 0.f, 0.f);
        o[3] = make_float4(0.f, 0.f, 0.f, 0.f);
    } else {
        eid[pos] = e;
        srcs[pos] = src[e];
    }
}

// spans[i] = number of 64-slot waves node i's CSR segment touches
__global__ __launch_bounds__(256) void spans_kernel(
        const int* __restrict__ off, int* __restrict__ spans, int N) {
    int i = blockIdx.x * blockDim.x + threadIdx.x;
    if (i >= N) return;
    int k0 = off[i], k1 = off[i + 1];
    spans[i] = (k1 > k0) ? (((k1 - 1) >> 6) - (k0 >> 6) + 1) : 0;
}

// ---------------- MFMA nodeA: A[n] = h[n] @ Wm1 + bm (layer-0 init + fallback) ----------------
__global__ __launch_bounds__(256) void nodeA_mfma_kernel(
        const short* __restrict__ W1T, const float* __restrict__ bm,
        const float* __restrict__ h, float* __restrict__ A, int N) {
    __shared__ short lds_w[64 * 72];
    __shared__ short lds_x[4][64 * 72];
    const int tid = threadIdx.x, wid = tid >> 6, lane = tid & 63;
    const int r = lane & 15, q = lane >> 4;
    const int nb0 = blockIdx.x * 256 + wid * 64;

#pragma unroll
    for (int j = 0; j < 2; ++j) {
        int f8 = (tid * 2 + j) * 8;
        int row = f8 >> 6, k = f8 & 63;
        *(uint4*)&lds_w[row * 72 + k] = ((const uint4*)W1T)[tid * 2 + j];
    }
    short* xt = &lds_x[wid][0];
#pragma unroll 1
    for (int it = 0; it < 16; ++it) {
        int f4 = it * 64 + lane;
        int node = f4 >> 4, c4 = f4 & 15;
        int gn = nb0 + node; if (gn >= N) gn = N - 1;
        float4 v = ((const float4*)h)[(size_t)gn * 16 + c4];
        *(uint2*)&xt[node * 72 + c4 * 4] =
            make_uint2(pack2bf(v.x, v.y), pack2bf(v.z, v.w));
    }
    __syncthreads();

    bfrag bg[4][2];
#pragma unroll
    for (int ni = 0; ni < 4; ++ni)
#pragma unroll
        for (int ki = 0; ki < 2; ++ki)
            bg[ni][ki] = *(const bfrag*)&lds_w[(ni * 16 + r) * 72 + ki * 32 + q * 8];
    float buv[4];
#pragma unroll
    for (int ni = 0; ni < 4; ++ni) buv[ni] = bm[ni * 16 + r];

    ffrag C[4][4];
#pragma unroll
    for (int mi = 0; mi < 4; ++mi) {
        bfrag af[2];
#pragma unroll
        for (int ki = 0; ki < 2; ++ki)
            af[ki] = *(const bfrag*)&xt[(mi * 16 + r) * 72 + ki * 32 + q * 8];
#pragma unroll
        for (int ni = 0; ni < 4; ++ni) {
            ffrag c = {buv[ni], buv[ni], buv[ni], buv[ni]};
            c = __builtin_amdgcn_mfma_f32_16x16x32_bf16(af[0], bg[ni][0], c, 0, 0, 0);
            c = __builtin_amdgcn_mfma_f32_16x16x32_bf16(af[1], bg[ni][1], c, 0, 0, 0);
            C[mi][ni] = c;
        }
    }
#pragma unroll
    for (int mi = 0; mi < 4; ++mi)
#pragma unroll
        for (int rr = 0; rr < 4; ++rr) {
            int gn = nb0 + mi * 16 + q * 4 + rr;
            if (gn < N) {
#pragma unroll
                for (int ni = 0; ni < 4; ++ni)
                    A[(size_t)gn * 64 + ni * 16 + r] = C[mi][ni][rr];
            }
        }
}

// ---------------- MFMA message (ev also MFMA now) + in-wave segmented reduction ----------------
// stage ef bf16 into ev-tile cols 0..31 (zero-padded); 16 MFMAs vs zero-padded WeT
// give C_ev = ef@We + be; relu -> bf16 back into tile (wave-private, in-order DS);
// then stage-2 as before: C = A[src] + ev@Wm2 via MFMA; C->LDS; segmented walk.
__global__ __launch_bounds__(256) void msg_mfma_red(
        const short* __restrict__ WeT, const float* __restrict__ be,
        const short* __restrict__ WbT, const float* __restrict__ rec,
        const float* __restrict__ A, float* __restrict__ pbuf,
        const int* __restrict__ off, const int* __restrict__ pstart, int E) {
    __shared__ short lds_wb[64 * 72];
    __shared__ short lds_we[64 * 36];
    __shared__ short lds_ev[4][64 * 72];
    __shared__ int   lds_src[4][64];
    const int tid = threadIdx.x;
    const int wid = tid >> 6, lane = tid & 63;
    const int w = blockIdx.x * 4 + wid;
    const int slot = w * 64 + lane;
    const int slotc = (slot < E) ? slot : (E - 1);

    for (int idx = tid; idx < 4096; idx += 256)
        lds_wb[(idx >> 6) * 72 + (idx & 63)] = WbT[idx];
    for (int idx = tid; idx < 2048; idx += 256)
        lds_we[(idx >> 5) * 36 + (idx & 31)] = WeT[idx];

    const float4* rp = (const float4*)(rec + (size_t)slotc * 16);
    float4 r0 = rp[0], r1 = rp[1], r2 = rp[2];
    int s  = __float_as_int(r0.x);
    int di = __float_as_int(r0.y);
    int pstv = pstart[di];
    int offv = off[di];
    lds_src[wid][lane] = s;

    // stage ef (bf16) into own tile row cols 0..31, zero pad 8..31
    short* evrow = &lds_ev[wid][lane * 72];
    *(uint4*)(evrow) = make_uint4(pack2bf(r0.z, r0.w), pack2bf(r1.x, r1.y),
                                  pack2bf(r1.z, r1.w), pack2bf(r2.x, r2.y));
    uint4 z4 = make_uint4(0u, 0u, 0u, 0u);
    *(uint4*)(evrow + 8)  = z4;
    *(uint4*)(evrow + 16) = z4;
    *(uint4*)(evrow + 24) = z4;
    __syncthreads();

    const int r = lane & 15, q = lane >> 4;
    short* evb = &lds_ev[wid][0];

    // stage-1 MFMA: C_ev = ef @ We + be  (K=32, padded)
    {
        bfrag afe[4], bge[4];
#pragma unroll
        for (int mi = 0; mi < 4; ++mi)
            afe[mi] = *(const bfrag*)(evb + (mi * 16 + r) * 72 + q * 8);
#pragma unroll
        for (int ni = 0; ni < 4; ++ni)
            bge[ni] = *(const bfrag*)(lds_we + (ni * 16 + r) * 36 + q * 8);
        float bev[4];
#pragma unroll
        for (int ni = 0; ni < 4; ++ni) bev[ni] = be[ni * 16 + r];
#pragma unroll
        for (int mi = 0; mi < 4; ++mi)
#pragma unroll
            for (int ni = 0; ni < 4; ++ni) {
                ffrag c = {bev[ni], bev[ni], bev[ni], bev[ni]};
                c = __builtin_amdgcn_mfma_f32_16x16x32_bf16(afe[mi], bge[ni], c, 0, 0, 0);
#pragma unroll
                for (int rr = 0; rr < 4; ++rr)
                    evb[(mi * 16 + q * 4 + rr) * 72 + ni * 16 + r] =
                        (short)f2bf_rne(fmaxf(c[rr], 0.f));
            }
    }
    // in-order per-wave DS: stage-1 writes complete before stage-2 reads

    // stage-2: C = A[src] + ev @ Wm2
    bfrag af[4][2], bg[4][2];
#pragma unroll
    for (int mi = 0; mi < 4; ++mi)
#pragma unroll
        for (int ki = 0; ki < 2; ++ki)
            af[mi][ki] = *(const bfrag*)(evb + (mi * 16 + r) * 72 + ki * 32 + q * 8);
#pragma unroll
    for (int ni = 0; ni < 4; ++ni)
#pragma unroll
        for (int ki = 0; ki < 2; ++ki)
            bg[ni][ki] = *(const bfrag*)(lds_wb + (ni * 16 + r) * 72 + ki * 32 + q * 8);

    ffrag C[4][4];
#pragma unroll
    for (int mi = 0; mi < 4; ++mi) {
        int srow[4];
#pragma unroll
        for (int rr = 0; rr < 4; ++rr)
            srow[rr] = lds_src[wid][mi * 16 + q * 4 + rr];
#pragma unroll
        for (int ni = 0; ni < 4; ++ni)
#pragma unroll
            for (int rr = 0; rr < 4; ++rr)
                C[mi][ni][rr] = A[(size_t)srow[rr] * 64 + ni * 16 + r];
    }

#pragma unroll
    for (int mi = 0; mi < 4; ++mi)
#pragma unroll
        for (int ni = 0; ni < 4; ++ni) {
            C[mi][ni] = __builtin_amdgcn_mfma_f32_16x16x32_bf16(
                af[mi][0], bg[ni][0], C[mi][ni], 0, 0, 0);
            C[mi][ni] = __builtin_amdgcn_mfma_f32_16x16x32_bf16(
                af[mi][1], bg[ni][1], C[mi][ni], 0, 0, 0);
        }

#pragma unroll
    for (int mi = 0; mi < 4; ++mi)
#pragma unroll
        for (int ni = 0; ni < 4; ++ni)
#pragma unroll
            for (int rr = 0; rr < 4; ++rr)
                evb[(mi * 16 + q * 4 + rr) * 72 + ni * 16 + r] =
                    (short)f2bf_rne(C[mi][ni][rr]);

    if (w * 64 < E) {
        int kmax = E - w * 64; if (kmax > 64) kmax = 64;
        int prevd = __shfl_up(di, 1);
        unsigned long long sm = __ballot(lane != 0 && di != prevd);
        int curp = __shfl(pstv, 0) + (w - (__shfl(offv, 0) >> 6));
        float acc = 0.f;
#pragma unroll
        for (int k = 0; k < 64; ++k) {
            if (sm & (1ull << k)) {
                pbuf[(size_t)curp * 64 + lane] = acc;
                acc = 0.f;
                curp = __shfl(pstv, k);
            }
            if (k < kmax) {
                float v = bf2f((unsigned short)evb[k * 72 + lane]);
                acc += fmaxf(v, 0.f);
            }
        }
        pbuf[(size_t)curp * 64 + lane] = acc;
    }
}

// ---------------- fused layer end: agg=fixup(pbuf); h=relu([h,agg]@Wu+bu)+h; A=h@Wm1'+bm' ----------------
// 2 waves/block, 64 nodes/wave. X tile [node][0..127] bf16 (h|agg); agg summed
// directly from pbuf partials during staging (fixup fused). After the update MFMA,
// h_new is rewritten bf16 into X cols 0..63 and a second MFMA produces next-layer A.
__global__ __launch_bounds__(128) void fused_update_kernel(
        const short* __restrict__ WuT, const float* __restrict__ bu,
        const short* __restrict__ W1T, const float* __restrict__ bmn,
        float* __restrict__ h, const float* __restrict__ pbuf,
        const int* __restrict__ off, const int* __restrict__ pstart,
        float* __restrict__ A, int N, int doA) {
    __shared__ short lds_wu[64 * 136];
    __shared__ short lds_w1[64 * 72];
    __shared__ short lds_x[2][64 * 136];
    const int tid = threadIdx.x, wid = tid >> 6, lane = tid & 63;
    const int r = lane & 15, q = lane >> 4;
    const int nb0 = blockIdx.x * 128 + wid * 64;

#pragma unroll
    for (int j = 0; j < 8; ++j) {
        int f8 = (tid * 8 + j) * 8;
        int row = f8 >> 7, k = f8 & 127;
        *(uint4*)&lds_wu[row * 136 + k] = ((const uint4*)WuT)[tid * 8 + j];
    }
    if (doA) {
#pragma unroll
        for (int j = 0; j < 4; ++j) {
            int f8 = (tid * 4 + j) * 8;
            int row = f8 >> 6, k = f8 & 63;
            *(uint4*)&lds_w1[row * 72 + k] = ((const uint4*)W1T)[tid * 4 + j];
        }
    }
    // stage X = [h | agg(pbuf-sum)]
    short* xt = &lds_x[wid][0];
#pragma unroll 1
    for (int it = 0; it < 32; ++it) {
        int f4 = it * 64 + lane;
        int node = f4 >> 5, c4 = f4 & 31;
        int gn = nb0 + node; if (gn >= N) gn = N - 1;
        float4 v;
        if (c4 < 16) {
            v = ((const float4*)h)[(size_t)gn * 16 + c4];
        } else {
            v = make_float4(0.f, 0.f, 0.f, 0.f);
            int k0 = off[gn], k1 = off[gn + 1];
            if (k1 > k0) {
                int nsp = ((k1 - 1) >> 6) - (k0 >> 6) + 1;
                int p = pstart[gn];
                for (int j = 0; j < nsp; ++j) {
                    float4 pv = ((const float4*)pbuf)[(size_t)(p + j) * 16 + (c4 - 16)];
                    v.x += pv.x; v.y += pv.y; v.z += pv.z; v.w += pv.w;
                }
            }
        }
        *(uint2*)&xt[node * 136 + c4 * 4] =
            make_uint2(pack2bf(v.x, v.y), pack2bf(v.z, v.w));
    }
    __syncthreads();

    bfrag bg[4][4];
#pragma unroll
    for (int ni = 0; ni < 4; ++ni)
#pragma unroll
        for (int ki = 0; ki < 4; ++ki)
            bg[ni][ki] = *(const bfrag*)&lds_wu[(ni * 16 + r) * 136 + ki * 32 + q * 8];
    float buv[4];
#pragma unroll
    for (int ni = 0; ni < 4; ++ni) buv[ni] = bu[ni * 16 + r];

    ffrag C[4][4];
#pragma unroll
    for (int mi = 0; mi < 4; ++mi) {
        bfrag af[4];
#pragma unroll
        for (int ki = 0; ki < 4; ++ki)
            af[ki] = *(const bfrag*)&xt[(mi * 16 + r) * 136 + ki * 32 + q * 8];
#pragma unroll
        for (int ni = 0; ni < 4; ++ni) {
            ffrag c = {buv[ni], buv[ni], buv[ni], buv[ni]};
#pragma unroll
            for (int ki = 0; ki < 4; ++ki)
                c = __builtin_amdgcn_mfma_f32_16x16x32_bf16(af[ki], bg[ni][ki], c, 0, 0, 0);
            C[mi][ni] = c;
        }
    }
    // epilogue: h_new = relu(C)+hold; store f32; rewrite bf16 into X cols 0..63
#pragma unroll
    for (int mi = 0; mi < 4; ++mi)
#pragma unroll
        for (int rr = 0; rr < 4; ++rr) {
            int nl = mi * 16 + q * 4 + rr;
            int gn = nb0 + nl;
#pragma unroll
            for (int ni = 0; ni < 4; ++ni) {
                int xi = nl * 136 + ni * 16 + r;
                float hold = bf2f((unsigned short)xt[xi]);
                float hnew = fmaxf(C[mi][ni][rr], 0.f) + hold;
                if (gn < N) h[(size_t)gn * 64 + ni * 16 + r] = hnew;
                if (doA) xt[xi] = (short)f2bf_rne(hnew);
            }
        }

    if (doA) {
        // next-layer A = h_new @ Wm1' + bm'   (wave-private X, in-order DS)
        bfrag bg1[4][2];
#pragma unroll
        for (int ni = 0; ni < 4; ++ni)
#pragma unroll
            for (int ki = 0; ki < 2; ++ki)
                bg1[ni][ki] = *(const bfrag*)&lds_w1[(ni * 16 + r) * 72 + ki * 32 + q * 8];
        float bmv[4];
#pragma unroll
        for (int ni = 0; ni < 4; ++ni) bmv[ni] = bmn[ni * 16 + r];
#pragma unroll
        for (int mi = 0; mi < 4; ++mi) {
            bfrag af1[2];
#pragma unroll
            for (int ki = 0; ki < 2; ++ki)
                af1[ki] = *(const bfrag*)&xt[(mi * 16 + r) * 136 + ki * 32 + q * 8];
#pragma unroll
            for (int ni = 0; ni < 4; ++ni) {
                ffrag c = {bmv[ni], bmv[ni], bmv[ni], bmv[ni]};
                c = __builtin_amdgcn_mfma_f32_16x16x32_bf16(af1[0], bg1[ni][0], c, 0, 0, 0);
                c = __builtin_amdgcn_mfma_f32_16x16x32_bf16(af1[1], bg1[ni][1], c, 0, 0, 0);
#pragma unroll
                for (int rr = 0; rr < 4; ++rr) {
                    int gn = nb0 + mi * 16 + q * 4 + rr;
                    if (gn < N) A[(size_t)gn * 64 + ni * 16 + r] = c[rr];
                }
            }
        }
    }
}

// ---------------- update (fallback path only) ----------------
__global__ __launch_bounds__(128) void update_mfma_kernel(
        const short* __restrict__ WuT, const float* __restrict__ bu,
        float* __restrict__ h, const float* __restrict__ agg, int N) {
    __shared__ short lds_w[64 * 136];
    __shared__ short lds_x[2][64 * 136];
    const int tid = threadIdx.x, wid = tid >> 6, lane = tid & 63;
    const int r = lane & 15, q = lane >> 4;
    const int nb0 = blockIdx.x * 128 + wid * 64;
#pragma unroll
    for (int j = 0; j < 8; ++j) {
        int f8 = (tid * 8 + j) * 8;
        int row = f8 >> 7, k = f8 & 127;
        *(uint4*)&lds_w[row * 136 + k] = ((const uint4*)WuT)[tid * 8 + j];
    }
    short* xt = &lds_x[wid][0];
#pragma unroll 1
    for (int it = 0; it < 32; ++it) {
        int f4 = it * 64 + lane;
        int node = f4 >> 5, c4 = f4 & 31;
        int gn = nb0 + node; if (gn >= N) gn = N - 1;
        const float4* src = (c4 < 16)
            ? ((const float4*)h + (size_t)gn * 16 + c4)
            : ((const float4*)agg + (size_t)gn * 16 + (c4 - 16));
        float4 v = *src;
        *(uint2*)&xt[node * 136 + c4 * 4] =
            make_uint2(pack2bf(v.x, v.y), pack2bf(v.z, v.w));
    }
    __syncthreads();
    bfrag bg[4][4];
#pragma unroll
    for (int ni = 0; ni < 4; ++ni)
#pragma unroll
        for (int ki = 0; ki < 4; ++ki)
            bg[ni][ki] = *(const bfrag*)&lds_w[(ni * 16 + r) * 136 + ki * 32 + q * 8];
    float buv[4];
#pragma unroll
    for (int ni = 0; ni < 4; ++ni) buv[ni] = bu[ni * 16 + r];
    ffrag C[4][4];
#pragma unroll
    for (int mi = 0; mi < 4; ++mi) {
        bfrag af[4];
#pragma unroll
        for (int ki = 0; ki < 4; ++ki)
            af[ki] = *(const bfrag*)&xt[(mi * 16 + r) * 136 + ki * 32 + q * 8];
#pragma unroll
        for (int ni = 0; ni < 4; ++ni) {
            ffrag c = {buv[ni], buv[ni], buv[ni], buv[ni]};
#pragma unroll
            for (int ki = 0; ki < 4; ++ki)
                c = __builtin_amdgcn_mfma_f32_16x16x32_bf16(af[ki], bg[ni][ki], c, 0, 0, 0);
            C[mi][ni] = c;
        }
    }
#pragma unroll
    for (int mi = 0; mi < 4; ++mi)
#pragma unroll
        for (int rr = 0; rr < 4; ++rr) {
            int nl = mi * 16 + q * 4 + rr;
            int gn = nb0 + nl;
            if (gn < N) {
#pragma unroll
                for (int ni = 0; ni < 4; ++ni) {
                    float hold = bf2f((unsigned short)xt[nl * 136 + ni * 16 + r]);
                    h[(size_t)gn * 64 + ni * 16 + r] =
                        fmaxf(C[mi][ni][rr], 0.f) + hold;
                }
            }
        }
}

// ---------------- fallback gather (tiny ws; R3 structure) ----------------
__global__ __launch_bounds__(256) void gather_msg_fallback(
        const float* __restrict__ Wm2, const float* __restrict__ We,
        const float* __restrict__ be, const void* __restrict__ ef,
        const int* __restrict__ srcs, const int* __restrict__ eid,
        const int* __restrict__ off, const float* __restrict__ A,
        float* __restrict__ agg, int N, const int* __restrict__ flagp) {
    int i = blockIdx.x * blockDim.x + threadIdx.x;
    if (i >= N) return;
    int isf32 = *flagp;
    int k0 = off[i], k1 = off[i + 1];
    float acc[64];
#pragma unroll
    for (int c = 0; c < 64; ++c) acc[c] = 0.f;
    for (int k = k0; k < k1; ++k) {
        int s = srcs[k];
        int e = eid[k];
        const float4* a4 = (const float4*)(A + (size_t)s * 64);
        float t[64];
#pragma unroll
        for (int c = 0; c < 16; ++c) {
            float4 v = a4[c];
            t[4 * c] = v.x; t[4 * c + 1] = v.y; t[4 * c + 2] = v.z; t[4 * c + 3] = v.w;
        }
        float efv[8];
        if (isf32) {
            const float4* e4 = (const float4*)ef + (size_t)e * 2;
            float4 ra = e4[0], rb = e4[1];
            efv[0]=ra.x; efv[1]=ra.y; efv[2]=ra.z; efv[3]=ra.w;
            efv[4]=rb.x; efv[5]=rb.y; efv[6]=rb.z; efv[7]=rb.w;
        } else {
            uint4 rr = ((const uint4*)ef)[e];
            efv[0]=bflo(rr.x); efv[1]=bfhi(rr.x); efv[2]=bflo(rr.y); efv[3]=bfhi(rr.y);
            efv[4]=bflo(rr.z); efv[5]=bfhi(rr.z); efv[6]=bflo(rr.w); efv[7]=bfhi(rr.w);
        }
#pragma unroll 1
        for (int d0 = 0; d0 < 64; d0 += 8) {
            float ev[8];
#pragma unroll
            for (int dd = 0; dd < 8; ++dd) {
                float a = be[d0 + dd];
#pragma unroll
                for (int kk = 0; kk < 8; ++kk) a = fmaf(efv[kk], We[kk * 64 + d0 + dd], a);
                ev[dd] = fmaxf(a, 0.f);
            }
#pragma unroll
            for (int dd = 0; dd < 8; ++dd) {
                const float* w = Wm2 + (d0 + dd) * 64;
#pragma unroll
                for (int c = 0; c < 64; ++c) t[c] = fmaf(ev[dd], w[c], t[c]);
            }
        }
#pragma unroll
        for (int c = 0; c < 64; ++c) acc[c] += fmaxf(t[c], 0.f);
    }
    float4* o4 = (float4*)(agg + (size_t)i * 64);
#pragma unroll
    for (int c = 0; c < 16; ++c)
        o4[c] = make_float4(acc[4 * c], acc[4 * c + 1], acc[4 * c + 2], acc[4 * c + 3]);
}

// ---------------- scores: 4 threads per pair + 4-lane shuffle reduction ----------------
__global__ __launch_bounds__(256) void scores_kernel(
        const float* __restrict__ Ws1, const float* __restrict__ bs1,
        const float* __restrict__ Ws2, const float* __restrict__ bs2,
        const int* __restrict__ ods, const int* __restrict__ odd,
        const float* __restrict__ h, void* __restrict__ out, int P,
        const int* __restrict__ flagp) {
    int tid = blockIdx.x * blockDim.x + threadIdx.x;
    int p = tid >> 2, q = tid & 3;
    if (p >= P) return;
    const int cq = q * 16;
    int s = ods[p], d = odd[p];
    float acc[16];
#pragma unroll
    for (int c = 0; c < 16; ++c) acc[c] = bs1[cq + c];
    const float4* hs4 = (const float4*)(h + (size_t)s * 64);
    const float4* hd4 = (const float4*)(h + (size_t)d * 64);
#pragma unroll 1
    for (int j0 = 0; j0 < 64; j0 += 8) {
        float4 xa = hs4[j0 >> 2], xb = hs4[(j0 >> 2) + 1];
        float x[8] = {xa.x, xa.y, xa.z, xa.w, xb.x, xb.y, xb.z, xb.w};
#pragma unroll
        for (int jj = 0; jj < 8; ++jj) {
            const float* w = Ws1 + (j0 + jj) * 64 + cq;
#pragma unroll
            for (int c = 0; c < 16; ++c) acc[c] = fmaf(x[jj], w[c], acc[c]);
        }
    }
#pragma unroll 1
    for (int j0 = 0; j0 < 64; j0 += 8) {
        float4 xa = hd4[j0 >> 2], xb = hd4[(j0 >> 2) + 1];
        float x[8] = {xa.x, xa.y, xa.z, xa.w, xb.x, xb.y, xb.z, xb.w};
#pragma unroll
        for (int jj = 0; jj < 8; ++jj) {
            const float* w = Ws1 + (64 + j0 + jj) * 64 + cq;
#pragma unroll
            for (int c = 0; c < 16; ++c) acc[c] = fmaf(x[jj], w[c], acc[c]);
        }
    }
    float part = 0.f;
#pragma unroll
    for (int c = 0; c < 16; ++c) part = fmaf(fmaxf(acc[c], 0.f), Ws2[cq + c], part);
    part += __shfl_xor(part, 1, 4);
    part += __shfl_xor(part, 2, 4);
    if (q == 0) {
        float score = part + bs2[0];
        if (*flagp) ((float*)out)[p] = score;
        else ((__hip_bfloat16*)out)[p] = __float2bfloat16(score);
    }
}

// ---------------- graph embed ----------------
__global__ __launch_bounds__(256) void embed_kernel(
        const float* __restrict__ h, float* __restrict__ gsum, int N) {
    __shared__ float red[256];
    int c = threadIdx.x & 63;
    int sub = threadIdx.x >> 6;   // 0..3
    float a = 0.f;
    for (int i = blockIdx.x * 4 + sub; i < N; i += gridDim.x * 4)
        a += h[(size_t)i * 64 + c];
    red[threadIdx.x] = a;
    __syncthreads();
    if (threadIdx.x < 64) {
        float t = red[threadIdx.x] + red[threadIdx.x + 64] +
                  red[threadIdx.x + 128] + red[threadIdx.x + 192];
        unsafeAtomicAdd(&gsum[threadIdx.x], t);
    }
}

// ---------------- dynamic-K head ----------------
__global__ void khead_kernel(const float* __restrict__ ws,
                             void* __restrict__ out, int N, int P,
                             const int* __restrict__ flagp) {
    if (threadIdx.x != 0 || blockIdx.x != 0) return;
    float x[68];
    float invN = 1.f / (float)N;
#pragma unroll
    for (int c = 0; c < 64; ++c) x[c] = ws[OFF_GSUM + c] * invN;
#pragma unroll
    for (int k = 0; k < 4; ++k) x[64 + k] = ws[OFF_TS + k];
    float h1[32];
    for (int j = 0; j < 32; ++j) {
        float a = ws[OFF_BK1 + j];
        for (int i = 0; i < 68; ++i) a = fmaf(x[i], ws[OFF_WK1 + i * 32 + j], a);
        h1[j] = fmaxf(a, 0.f);
    }
    float h2[16];
    for (int k2 = 0; k2 < 16; ++k2) {
        float a = ws[OFF_BK2 + k2];
        for (int j = 0; j < 32; ++j) a = fmaf(h1[j], ws[OFF_WK2 + j * 16 + k2], a);
        h2[k2] = fmaxf(a, 0.f);
    }
    float raw = ws[OFF_BK3];
    for (int k2 = 0; k2 < 16; ++k2) raw = fmaf(h2[k2], ws[OFF_WK3 + k2], raw);
    float sig = 1.f / (1.f + expf(-raw));
    float k = 1.f + 49.f * sig;
    if (*flagp) ((float*)out)[P] = k;
    else ((__hip_bfloat16*)out)[P] = __float2bfloat16(k);
}

extern "C" void kernel_launch(void* const* d_in, const int* in_sizes, int n_in,
                              void* d_out, int out_size, void* d_ws, size_t ws_size,
                              hipStream_t stream) {
    const void* nf = d_in[0];
    const int*  ei = (const int*)d_in[1];
    const void* ef = d_in[2];
    const int*  od = (const int*)d_in[3];
    float* ws = (float*)d_ws;

    const int N = in_sizes[0] / 16;   // 50000
    const int E = in_sizes[1] / 2;    // 1200000
    const int P = in_sizes[3] / 2;    // 10000

    // layout: h, agg, A; deg/spans, off, cursor, pstart, eid, srcs, Wtrans; rec; pbuf
    float* h      = ws + OFF_H;
    float* agg    = h + (size_t)N * 64;
    float* A      = agg + (size_t)N * 64;
    int*   deg    = (int*)(A + (size_t)N * 64);   // N (reused as spans)
    int*   off    = deg + N;                      // N+1
    int*   cursor = off + N + 1;                  // N
    int*   pstart = cursor + N;                   // N+1
    int*   eid    = pstart + N + 1;               // E (fallback only)
    int*   srcs   = eid + E;                      // E (fallback only)
    short* WbT    = (short*)(srcs + E);           // 51200 shorts: WbT|W1T|WuT|WeT
    short* W1T    = WbT + 12288;
    short* WuT    = WbT + 24576;
    short* WeT    = WbT + 49152;
    int*   flag   = (int*)(ws + OFF_FLAG);
    int*   bsum   = (int*)(ws + OFF_BSUM);
    int*   boff   = (int*)(ws + OFF_BOFF);

    size_t fsofar = (size_t)OFF_H + 3 * (size_t)N * 64
                  + (size_t)(N + (N + 1) + N + (N + 1) + E + E) + 25600;
    size_t recOff = (fsofar + 15) & ~(size_t)15;          // 64-B align records
    float* rec = ws + recOff;
    size_t pbufOff = recOff + (size_t)E * 16;
    float* pbuf = ws + pbufOff;
    long pbufRows = (long)N + E / 64 + 128;
    size_t needBytes = (pbufOff + (size_t)pbufRows * 64) * sizeof(float);
    const bool big = (ws_size >= needBytes);

    const int* srcv = ei;
    const int* dstv = ei + E;

    // 0. dtype detect
    detect_dtype_kernel<<<1, 64, 0, stream>>>((const unsigned short*)nf, flag);

    // 1. convert weights to f32 in ws; build transposed bf16 weights
    ConvArgs ca;
    const int srcidx[19] = {5, 6, 7, 8, 9, 10, 11, 12, 13, 14, 15, 16, 17, 18, 19, 20, 21, 22, 4};
    const int wsoff[19]  = {OFF_WN, OFF_BN, OFF_WE, OFF_BE, OFF_WM, OFF_BM, OFF_WU, OFF_BU,
                            OFF_WS1, OFF_BS1, OFF_WS2, OFF_BS2, OFF_WK1, OFF_BK1, OFF_WK2,
                            OFF_BK2, OFF_WK3, OFF_BK3, OFF_TS};
    int maxn = 0;
    for (int i = 0; i < 19; ++i) {
        ca.src[i] = d_in[srcidx[i]];
        ca.off[i] = wsoff[i];
        ca.n[i]   = in_sizes[srcidx[i]];
        if (ca.n[i] > maxn) maxn = ca.n[i];
    }
    dim3 cgrid((maxn + 255) / 256, 19);
    convert_all_kernel<<<cgrid, 256, 0, stream>>>(ca, ws, flag);
    wtrans_prep_kernel<<<200, 256, 0, stream>>>(ws, WbT);

    // 2. node projection
    node_proj_kernel<<<(N * 64 + 255) / 256, 256, 0, stream>>>(nf, ws, h, N, flag);

    // 3. build CSR by dst (once). fill writes 64-B records in big mode.
    hipMemsetAsync(deg, 0, (size_t)N * sizeof(int), stream);
    count_kernel<<<(E + 255) / 256, 256, 0, stream>>>(dstv, deg, E);
    int nb = (N + 255) / 256;
    scan_blocks_kernel<<<nb, 256, 0, stream>>>(deg, cursor, bsum, N);
    scan_bsum_kernel<<<1, 256, 0, stream>>>(bsum, boff, nb);
    scan_finalize_kernel<<<nb, 256, 0, stream>>>(deg, cursor, boff, off, cursor, N, E);
    fill_kernel<<<(E + 255) / 256, 256, 0, stream>>>(
        srcv, dstv, ef, cursor, eid, srcs, rec, E, big ? 1 : 0, flag);

    // 3b. pstart = exclusive scan of wave-span counts (big path only)
    if (big) {
        spans_kernel<<<nb, 256, 0, stream>>>(off, deg, N);       // deg := spans
        scan_blocks_kernel<<<nb, 256, 0, stream>>>(deg, cursor, bsum, N);
        scan_bsum_kernel<<<1, 256, 0, stream>>>(bsum, boff, nb);
        scan_finalize_kernel<<<nb, 256, 0, stream>>>(deg, cursor, boff, pstart, cursor, N, 0);
    }

    // 4. GNN layers
    const int mblocks = (E + 255) / 256;
    const int ablocks = (N + 255) / 256;
    const int ublocks = (N + 127) / 128;
    // initial A (layer 0)
    nodeA_mfma_kernel<<<ablocks, 256, 0, stream>>>(
        W1T, ws + OFF_BM, h, A, N);
    for (int l = 0; l < 3; ++l) {
        if (big) {
            msg_mfma_red<<<mblocks, 256, 0, stream>>>(
                WeT, ws + OFF_BE, WbT + l * 4096, rec, A, pbuf, off, pstart, E);
            int nl = (l < 2) ? (l + 1) : 0;
            fused_update_kernel<<<ublocks, 128, 0, stream>>>(
                WuT + l * 8192, ws + OFF_BU + l * 64,
                W1T + nl * 4096, ws + OFF_BM + nl * 64,
                h, pbuf, off, pstart, A, N, (l < 2) ? 1 : 0);
        } else {
            const float* Wm2 = ws + OFF_WM + l * 8192 + 4096;
            gather_msg_fallback<<<(N + 255) / 256, 256, 0, stream>>>(
                Wm2, ws + OFF_WE, ws + OFF_BE, ef, srcs, eid, off, A, agg, N, flag);
            update_mfma_kernel<<<ublocks, 128, 0, stream>>>(
                WuT + l * 8192, ws + OFF_BU + l * 64, h, agg, N);
            if (l < 2)
                nodeA_mfma_kernel<<<ablocks, 256, 0, stream>>>(
                    W1T + (l + 1) * 4096, ws + OFF_BM + (l + 1) * 64, h, A, N);
        }
    }

    // 5. per-flow scores
    scores_kernel<<<(P * 4 + 255) / 256, 256, 0, stream>>>(
        ws + OFF_WS1, ws + OFF_BS1, ws + OFF_WS2, ws + OFF_BS2,
        od, od + P, h, d_out, P, flag);

    // 6. graph embedding + dynamic-K head
    hipMemsetAsync(ws + OFF_GSUM, 0, 64 * sizeof(float), stream);
    embed_kernel<<<256, 256, 0, stream>>>(h, ws + OFF_GSUM, N);
    khead_kernel<<<1, 64, 0, stream>>>(ws, d_out, N, P, flag);
}

// Round 12
// 751.749 us; speedup vs baseline: 1.1053x; 1.1053x over previous
//
#include <hip/hip_runtime.h>
#include <hip/hip_bf16.h>

// ---------------- workspace layout (float offsets, fixed small region) ----------------
#define OFF_WN   0
#define OFF_BN   1024
#define OFF_WE   1088
#define OFF_BE   1600
#define OFF_WM   1664            // 3 * 128 * 64
#define OFF_BM   26240           // 3 * 64
#define OFF_WU   26432           // 3 * 128 * 64
#define OFF_BU   51008           // 3 * 64
#define OFF_WS1  51200           // 128 * 64
#define OFF_BS1  59392
#define OFF_WS2  59456
#define OFF_BS2  59520
#define OFF_WK1  59521           // 68 * 32
#define OFF_BK1  61697
#define OFF_WK2  61729           // 32 * 16
#define OFF_BK2  62241
#define OFF_WK3  62257
#define OFF_BK3  62273
#define OFF_TS   62274           // traffic stats (4)
#define OFF_GSUM 62278           // graph-embed accumulator (64)
#define OFF_FLAG 62344           // dtype flag: 1 = inputs are f32, 0 = bf16
#define OFF_BSUM 62400           // block sums for scan (<=400)
#define OFF_BOFF 62900           // block offsets for scan (<=400)
#define OFF_H    65536           // big arrays start here (see kernel_launch)

typedef __attribute__((ext_vector_type(8))) short bfrag;   // 8 bf16 (4 VGPRs)
typedef __attribute__((ext_vector_type(4))) float ffrag;   // 4 f32 acc

__device__ __forceinline__ float bf2f(unsigned short u) {
    unsigned int i = ((unsigned int)u) << 16;
    float f;
    __builtin_memcpy(&f, &i, sizeof(f));
    return f;
}
__device__ __forceinline__ float bflo(unsigned int u) {
    unsigned int i = u << 16;
    float f; __builtin_memcpy(&f, &i, sizeof(f)); return f;
}
__device__ __forceinline__ float bfhi(unsigned int u) {
    unsigned int i = u & 0xffff0000u;
    float f; __builtin_memcpy(&f, &i, sizeof(f)); return f;
}
__device__ __forceinline__ unsigned int f2bf_rne(float f) {
    unsigned int u; __builtin_memcpy(&u, &f, 4);
    return (u + 0x7fffu + ((u >> 16) & 1u)) >> 16;
}
__device__ __forceinline__ unsigned int pack2bf(float a, float b) {
    return f2bf_rne(a) | (f2bf_rne(b) << 16);
}

// ---------------- dtype sniffer (R2 evidence: takes the f32 branch) ----------------
__global__ void detect_dtype_kernel(const unsigned short* __restrict__ nf,
                                    int* __restrict__ flag) {
    int t = threadIdx.x;  // 64 threads
    float m = 0.f;
    for (int i = t; i < 1024; i += 64) {
        float v = fabsf(bf2f(nf[i]));
        if (!isnan(v)) m = fmaxf(m, v);
        else m = 1e30f;
    }
    for (int o = 32; o > 0; o >>= 1) m = fmaxf(m, __shfl_down(m, o));
    if (t == 0) flag[0] = (m > 1e6f) ? 1 : 0;
}

// ---------------- weight conversion ----------------
struct ConvArgs {
    const void* src[19];
    int off[19];
    int n[19];
};

__global__ __launch_bounds__(256) void convert_all_kernel(
        ConvArgs a, float* __restrict__ ws, const int* __restrict__ flagp) {
    int isf32 = *flagp;
    int ai = blockIdx.y;
    int i  = blockIdx.x * blockDim.x + threadIdx.x;
    if (i < a.n[ai]) {
        float v = isf32 ? ((const float*)a.src[ai])[i]
                        : bf2f(((const unsigned short*)a.src[ai])[i]);
        ws[a.off[ai] + i] = v;
    }
}

// ---------------- transposed bf16 weight prep ----------------
// WbT[l][n*64+k]  = Wm2[l][k][n]         (12288 shorts)
// W1T[l][n*64+k]  = Wm1[l][k][n]         (12288 shorts)
// WuT[l][n*128+k] = Wu[l][k][n]          (24576 shorts)
// WeT[n*32+k]     = k<8 ? We[k][n] : 0   (2048 shorts, zero-padded K)
// Ws1T[n*128+k]   = Ws1[k][n]            (8192 shorts)
__global__ __launch_bounds__(256) void wtrans_prep_kernel(
        const float* __restrict__ ws, short* __restrict__ Wb) {
    int idx = blockIdx.x * 256 + threadIdx.x;
    if (idx < 12288) {
        int l = idx >> 12, rem = idx & 4095, n = rem >> 6, k = rem & 63;
        Wb[idx] = (short)f2bf_rne(ws[OFF_WM + l * 8192 + 4096 + k * 64 + n]);
    } else if (idx < 24576) {
        int j = idx - 12288;
        int l = j >> 12, rem = j & 4095, n = rem >> 6, k = rem & 63;
        Wb[idx] = (short)f2bf_rne(ws[OFF_WM + l * 8192 + k * 64 + n]);
    } else if (idx < 49152) {
        int j = idx - 24576;
        int l = j >> 13, rem = j & 8191, n = rem >> 7, k = rem & 127;
        Wb[idx] = (short)f2bf_rne(ws[OFF_WU + l * 8192 + k * 64 + n]);
    } else if (idx < 51200) {
        int j = idx - 49152;
        int n = j >> 5, k = j & 31;
        Wb[idx] = (k < 8) ? (short)f2bf_rne(ws[OFF_WE + k * 64 + n]) : (short)0;
    } else if (idx < 59392) {
        int j = idx - 51200;
        int n = j >> 7, k = j & 127;
        Wb[idx] = (short)f2bf_rne(ws[OFF_WS1 + k * 64 + n]);
    }
}

// ---------------- node projection: h = relu(nf @ Wn + bn) ----------------
__global__ __launch_bounds__(256) void node_proj_kernel(
        const void* __restrict__ nf, const float* __restrict__ ws,
        float* __restrict__ h, int N, const int* __restrict__ flagp) {
    int idx = blockIdx.x * blockDim.x + threadIdx.x;
    if (idx >= N * 64) return;
    int isf32 = *flagp;
    int i = idx >> 6, c = idx & 63;
    const float* Wn = ws + OFF_WN;
    float acc = ws[OFF_BN + c];
    float x[16];
    if (isf32) {
        const float* row = (const float*)nf + (size_t)i * 16;
#pragma unroll
        for (int k = 0; k < 16; ++k) x[k] = row[k];
    } else {
        const unsigned short* row = (const unsigned short*)nf + (size_t)i * 16;
#pragma unroll
        for (int k = 0; k < 16; ++k) x[k] = bf2f(row[k]);
    }
#pragma unroll
    for (int k = 0; k < 16; ++k) acc = fmaf(x[k], Wn[k * 64 + c], acc);
    h[idx] = fmaxf(acc, 0.f);
}

// ---------------- CSR build ----------------
__global__ __launch_bounds__(256) void count_kernel(
        const int* __restrict__ dst, int* __restrict__ deg, int E) {
    int e = blockIdx.x * blockDim.x + threadIdx.x;
    if (e < E) atomicAdd(&deg[dst[e]], 1);
}

__global__ __launch_bounds__(256) void scan_blocks_kernel(
        const int* __restrict__ deg, int* __restrict__ incl,
        int* __restrict__ bsum, int N) {
    int tid = threadIdx.x;
    int gid = blockIdx.x * 256 + tid;
    int v = (gid < N) ? deg[gid] : 0;
    int lane = tid & 63, w = tid >> 6;
    int x = v;
#pragma unroll
    for (int o = 1; o < 64; o <<= 1) {
        int y = __shfl_up(x, o);
        if (lane >= o) x += y;
    }
    __shared__ int wsum[4];
    __shared__ int woff[4];
    if (lane == 63) wsum[w] = x;
    __syncthreads();
    if (tid == 0) {
        int a = 0;
#pragma unroll
        for (int i = 0; i < 4; ++i) { woff[i] = a; a += wsum[i]; }
    }
    __syncthreads();
    x += woff[w];
    if (gid < N) incl[gid] = x;
    if (tid == 255) bsum[blockIdx.x] = x;
}

__global__ __launch_bounds__(256) void scan_bsum_kernel(
        const int* __restrict__ bsum, int* __restrict__ boff, int nb) {
    __shared__ int sh[256];
    int tid = threadIdx.x;
    int carry = 0;
    for (int base = 0; base < nb; base += 256) {
        int v = (base + tid < nb) ? bsum[base + tid] : 0;
        sh[tid] = v;
        __syncthreads();
        for (int o = 1; o < 256; o <<= 1) {
            int t = (tid >= o) ? sh[tid - o] : 0;
            __syncthreads();
            sh[tid] += t;
            __syncthreads();
        }
        if (base + tid < nb) boff[base + tid] = carry + sh[tid] - v;
        __syncthreads();
        carry += sh[255];
        __syncthreads();
    }
}

__global__ __launch_bounds__(256) void scan_finalize_kernel(
        const int* __restrict__ deg, const int* __restrict__ incl,
        const int* __restrict__ boff, int* __restrict__ out,
        int* __restrict__ cursor, int N, int tailval) {
    int gid = blockIdx.x * 256 + threadIdx.x;
    if (gid < N) {
        int ex = boff[blockIdx.x] + incl[gid] - deg[gid];
        out[gid] = ex;
        cursor[gid] = ex;
    }
    if (gid == 0) out[N] = tailval;
}

// fill CSR. big mode: one 64-B record {src,dst,ef[8],pad} per slot.
__global__ __launch_bounds__(256) void fill_kernel(
        const int* __restrict__ src, const int* __restrict__ dst,
        const void* __restrict__ ef, int* __restrict__ cursor,
        int* __restrict__ eid, int* __restrict__ srcs,
        float* __restrict__ rec, int E, int big,
        const int* __restrict__ flagp) {
    int e = blockIdx.x * blockDim.x + threadIdx.x;
    if (e >= E) return;
    int d = dst[e];
    int pos = atomicAdd(&cursor[d], 1);
    if (big) {
        float v[8];
        if (*flagp) {
            const float4* p = (const float4*)ef + (size_t)e * 2;
            float4 a = p[0], b = p[1];
            v[0]=a.x; v[1]=a.y; v[2]=a.z; v[3]=a.w;
            v[4]=b.x; v[5]=b.y; v[6]=b.z; v[7]=b.w;
        } else {
            uint4 r = ((const uint4*)ef)[e];
            v[0]=bflo(r.x); v[1]=bfhi(r.x); v[2]=bflo(r.y); v[3]=bfhi(r.y);
            v[4]=bflo(r.z); v[5]=bfhi(r.z); v[6]=bflo(r.w); v[7]=bfhi(r.w);
        }
        float4* o = (float4*)(rec + (size_t)pos * 16);
        o[0] = make_float4(__int_as_float(src[e]), __int_as_float(d), v[0], v[1]);
        o[1] = make_float4(v[2], v[3], v[4], v[5]);
        o[2] = make_float4(v[6], v[7], 0.f, 0.f);
        o[3] = make_float4(0.f, 0.f, 0.f, 0.f);
    } else {
        eid[pos] = e;
        srcs[pos] = src[e];
    }
}

// spans[i] = number of 64-slot waves node i's CSR segment touches
__global__ __launch_bounds__(256) void spans_kernel(
        const int* __restrict__ off, int* __restrict__ spans, int N) {
    int i = blockIdx.x * blockDim.x + threadIdx.x;
    if (i >= N) return;
    int k0 = off[i], k1 = off[i + 1];
    spans[i] = (k1 > k0) ? (((k1 - 1) >> 6) - (k0 >> 6) + 1) : 0;
}

// ---------------- MFMA nodeA: A[n] = h[n] @ Wm1 + bm ----------------
__global__ __launch_bounds__(256) void nodeA_mfma_kernel(
        const short* __restrict__ W1T, const float* __restrict__ bm,
        const float* __restrict__ h, float* __restrict__ A, int N) {
    __shared__ short lds_w[64 * 72];
    __shared__ short lds_x[4][64 * 72];
    const int tid = threadIdx.x, wid = tid >> 6, lane = tid & 63;
    const int r = lane & 15, q = lane >> 4;
    const int nb0 = blockIdx.x * 256 + wid * 64;

#pragma unroll
    for (int j = 0; j < 2; ++j) {
        int f8 = (tid * 2 + j) * 8;
        int row = f8 >> 6, k = f8 & 63;
        *(uint4*)&lds_w[row * 72 + k] = ((const uint4*)W1T)[tid * 2 + j];
    }
    short* xt = &lds_x[wid][0];
#pragma unroll 1
    for (int it = 0; it < 16; ++it) {
        int f4 = it * 64 + lane;
        int node = f4 >> 4, c4 = f4 & 15;
        int gn = nb0 + node; if (gn >= N) gn = N - 1;
        float4 v = ((const float4*)h)[(size_t)gn * 16 + c4];
        *(uint2*)&xt[node * 72 + c4 * 4] =
            make_uint2(pack2bf(v.x, v.y), pack2bf(v.z, v.w));
    }
    __syncthreads();

    bfrag bg[4][2];
#pragma unroll
    for (int ni = 0; ni < 4; ++ni)
#pragma unroll
        for (int ki = 0; ki < 2; ++ki)
            bg[ni][ki] = *(const bfrag*)&lds_w[(ni * 16 + r) * 72 + ki * 32 + q * 8];
    float buv[4];
#pragma unroll
    for (int ni = 0; ni < 4; ++ni) buv[ni] = bm[ni * 16 + r];

    ffrag C[4][4];
#pragma unroll
    for (int mi = 0; mi < 4; ++mi) {
        bfrag af[2];
#pragma unroll
        for (int ki = 0; ki < 2; ++ki)
            af[ki] = *(const bfrag*)&xt[(mi * 16 + r) * 72 + ki * 32 + q * 8];
#pragma unroll
        for (int ni = 0; ni < 4; ++ni) {
            ffrag c = {buv[ni], buv[ni], buv[ni], buv[ni]};
            c = __builtin_amdgcn_mfma_f32_16x16x32_bf16(af[0], bg[ni][0], c, 0, 0, 0);
            c = __builtin_amdgcn_mfma_f32_16x16x32_bf16(af[1], bg[ni][1], c, 0, 0, 0);
            C[mi][ni] = c;
        }
    }
#pragma unroll
    for (int mi = 0; mi < 4; ++mi)
#pragma unroll
        for (int rr = 0; rr < 4; ++rr) {
            int gn = nb0 + mi * 16 + q * 4 + rr;
            if (gn < N) {
#pragma unroll
                for (int ni = 0; ni < 4; ++ni)
                    A[(size_t)gn * 64 + ni * 16 + r] = C[mi][ni][rr];
            }
        }
}

// ---------------- MFMA message (two-stage) + in-wave segmented reduction (R11, verified) ----------------
__global__ __launch_bounds__(256) void msg_mfma_red(
        const short* __restrict__ WeT, const float* __restrict__ be,
        const short* __restrict__ WbT, const float* __restrict__ rec,
        const float* __restrict__ A, float* __restrict__ pbuf,
        const int* __restrict__ off, const int* __restrict__ pstart, int E) {
    __shared__ short lds_wb[64 * 72];
    __shared__ short lds_we[64 * 36];
    __shared__ short lds_ev[4][64 * 72];
    __shared__ int   lds_src[4][64];
    const int tid = threadIdx.x;
    const int wid = tid >> 6, lane = tid & 63;
    const int w = blockIdx.x * 4 + wid;
    const int slot = w * 64 + lane;
    const int slotc = (slot < E) ? slot : (E - 1);

    for (int idx = tid; idx < 4096; idx += 256)
        lds_wb[(idx >> 6) * 72 + (idx & 63)] = WbT[idx];
    for (int idx = tid; idx < 2048; idx += 256)
        lds_we[(idx >> 5) * 36 + (idx & 31)] = WeT[idx];

    const float4* rp = (const float4*)(rec + (size_t)slotc * 16);
    float4 r0 = rp[0], r1 = rp[1], r2 = rp[2];
    int s  = __float_as_int(r0.x);
    int di = __float_as_int(r0.y);
    int pstv = pstart[di];
    int offv = off[di];
    lds_src[wid][lane] = s;

    short* evrow = &lds_ev[wid][lane * 72];
    *(uint4*)(evrow) = make_uint4(pack2bf(r0.z, r0.w), pack2bf(r1.x, r1.y),
                                  pack2bf(r1.z, r1.w), pack2bf(r2.x, r2.y));
    uint4 z4 = make_uint4(0u, 0u, 0u, 0u);
    *(uint4*)(evrow + 8)  = z4;
    *(uint4*)(evrow + 16) = z4;
    *(uint4*)(evrow + 24) = z4;
    __syncthreads();

    const int r = lane & 15, q = lane >> 4;
    short* evb = &lds_ev[wid][0];

    // stage-1 MFMA: C_ev = ef @ We + be  (K=32, padded)
    {
        bfrag afe[4], bge[4];
#pragma unroll
        for (int mi = 0; mi < 4; ++mi)
            afe[mi] = *(const bfrag*)(evb + (mi * 16 + r) * 72 + q * 8);
#pragma unroll
        for (int ni = 0; ni < 4; ++ni)
            bge[ni] = *(const bfrag*)(lds_we + (ni * 16 + r) * 36 + q * 8);
        float bev[4];
#pragma unroll
        for (int ni = 0; ni < 4; ++ni) bev[ni] = be[ni * 16 + r];
#pragma unroll
        for (int mi = 0; mi < 4; ++mi)
#pragma unroll
            for (int ni = 0; ni < 4; ++ni) {
                ffrag c = {bev[ni], bev[ni], bev[ni], bev[ni]};
                c = __builtin_amdgcn_mfma_f32_16x16x32_bf16(afe[mi], bge[ni], c, 0, 0, 0);
#pragma unroll
                for (int rr = 0; rr < 4; ++rr)
                    evb[(mi * 16 + q * 4 + rr) * 72 + ni * 16 + r] =
                        (short)f2bf_rne(fmaxf(c[rr], 0.f));
            }
    }

    // stage-2: C = A[src] + ev @ Wm2
    bfrag af[4][2], bg[4][2];
#pragma unroll
    for (int mi = 0; mi < 4; ++mi)
#pragma unroll
        for (int ki = 0; ki < 2; ++ki)
            af[mi][ki] = *(const bfrag*)(evb + (mi * 16 + r) * 72 + ki * 32 + q * 8);
#pragma unroll
    for (int ni = 0; ni < 4; ++ni)
#pragma unroll
        for (int ki = 0; ki < 2; ++ki)
            bg[ni][ki] = *(const bfrag*)(lds_wb + (ni * 16 + r) * 72 + ki * 32 + q * 8);

    ffrag C[4][4];
#pragma unroll
    for (int mi = 0; mi < 4; ++mi) {
        int srow[4];
#pragma unroll
        for (int rr = 0; rr < 4; ++rr)
            srow[rr] = lds_src[wid][mi * 16 + q * 4 + rr];
#pragma unroll
        for (int ni = 0; ni < 4; ++ni)
#pragma unroll
            for (int rr = 0; rr < 4; ++rr)
                C[mi][ni][rr] = A[(size_t)srow[rr] * 64 + ni * 16 + r];
    }

#pragma unroll
    for (int mi = 0; mi < 4; ++mi)
#pragma unroll
        for (int ni = 0; ni < 4; ++ni) {
            C[mi][ni] = __builtin_amdgcn_mfma_f32_16x16x32_bf16(
                af[mi][0], bg[ni][0], C[mi][ni], 0, 0, 0);
            C[mi][ni] = __builtin_amdgcn_mfma_f32_16x16x32_bf16(
                af[mi][1], bg[ni][1], C[mi][ni], 0, 0, 0);
        }

#pragma unroll
    for (int mi = 0; mi < 4; ++mi)
#pragma unroll
        for (int ni = 0; ni < 4; ++ni)
#pragma unroll
            for (int rr = 0; rr < 4; ++rr)
                evb[(mi * 16 + q * 4 + rr) * 72 + ni * 16 + r] =
                    (short)f2bf_rne(C[mi][ni][rr]);

    if (w * 64 < E) {
        int kmax = E - w * 64; if (kmax > 64) kmax = 64;
        int prevd = __shfl_up(di, 1);
        unsigned long long sm = __ballot(lane != 0 && di != prevd);
        int curp = __shfl(pstv, 0) + (w - (__shfl(offv, 0) >> 6));
        float acc = 0.f;
#pragma unroll
        for (int k = 0; k < 64; ++k) {
            if (sm & (1ull << k)) {
                pbuf[(size_t)curp * 64 + lane] = acc;
                acc = 0.f;
                curp = __shfl(pstv, k);
            }
            if (k < kmax) {
                float v = bf2f((unsigned short)evb[k * 72 + lane]);
                acc += fmaxf(v, 0.f);
            }
        }
        pbuf[(size_t)curp * 64 + lane] = acc;
    }
}

// fixup: agg[i] = sum of node i's partial rows (R10, verified); zero for deg-0 nodes
__global__ __launch_bounds__(256) void fixup_kernel(
        const float* __restrict__ pbuf, const int* __restrict__ off,
        const int* __restrict__ pstart, float* __restrict__ agg, int N) {
    int tid = blockIdx.x * blockDim.x + threadIdx.x;
    int i = tid >> 2, q = tid & 3;
    if (i >= N) return;
    int k0 = off[i], k1 = off[i + 1];
    float acc[16];
#pragma unroll
    for (int c = 0; c < 16; ++c) acc[c] = 0.f;
    if (k1 > k0) {
        int nsp = ((k1 - 1) >> 6) - (k0 >> 6) + 1;
        int p = pstart[i];
        for (int j = 0; j < nsp; ++j) {
            const float4* pr = (const float4*)(pbuf + (size_t)(p + j) * 64 + q * 16);
#pragma unroll
            for (int c = 0; c < 4; ++c) {
                float4 v = pr[c];
                acc[4 * c] += v.x; acc[4 * c + 1] += v.y;
                acc[4 * c + 2] += v.z; acc[4 * c + 3] += v.w;
            }
        }
    }
    float4* o4 = (float4*)(agg + (size_t)i * 64 + q * 16);
#pragma unroll
    for (int c = 0; c < 4; ++c)
        o4[c] = make_float4(acc[4 * c], acc[4 * c + 1], acc[4 * c + 2], acc[4 * c + 3]);
}

// ---------------- MFMA update: h = relu([h,agg] @ Wu + bu) + h (R10, verified) ----------------
__global__ __launch_bounds__(128) void update_mfma_kernel(
        const short* __restrict__ WuT, const float* __restrict__ bu,
        float* __restrict__ h, const float* __restrict__ agg, int N) {
    __shared__ short lds_w[64 * 136];
    __shared__ short lds_x[2][64 * 136];
    const int tid = threadIdx.x, wid = tid >> 6, lane = tid & 63;
    const int r = lane & 15, q = lane >> 4;
    const int nb0 = blockIdx.x * 128 + wid * 64;
#pragma unroll
    for (int j = 0; j < 8; ++j) {
        int f8 = (tid * 8 + j) * 8;
        int row = f8 >> 7, k = f8 & 127;
        *(uint4*)&lds_w[row * 136 + k] = ((const uint4*)WuT)[tid * 8 + j];
    }
    short* xt = &lds_x[wid][0];
#pragma unroll 1
    for (int it = 0; it < 32; ++it) {
        int f4 = it * 64 + lane;
        int node = f4 >> 5, c4 = f4 & 31;
        int gn = nb0 + node; if (gn >= N) gn = N - 1;
        const float4* src = (c4 < 16)
            ? ((const float4*)h + (size_t)gn * 16 + c4)
            : ((const float4*)agg + (size_t)gn * 16 + (c4 - 16));
        float4 v = *src;
        *(uint2*)&xt[node * 136 + c4 * 4] =
            make_uint2(pack2bf(v.x, v.y), pack2bf(v.z, v.w));
    }
    __syncthreads();
    bfrag bg[4][4];
#pragma unroll
    for (int ni = 0; ni < 4; ++ni)
#pragma unroll
        for (int ki = 0; ki < 4; ++ki)
            bg[ni][ki] = *(const bfrag*)&lds_w[(ni * 16 + r) * 136 + ki * 32 + q * 8];
    float buv[4];
#pragma unroll
    for (int ni = 0; ni < 4; ++ni) buv[ni] = bu[ni * 16 + r];
    ffrag C[4][4];
#pragma unroll
    for (int mi = 0; mi < 4; ++mi) {
        bfrag af[4];
#pragma unroll
        for (int ki = 0; ki < 4; ++ki)
            af[ki] = *(const bfrag*)&xt[(mi * 16 + r) * 136 + ki * 32 + q * 8];
#pragma unroll
        for (int ni = 0; ni < 4; ++ni) {
            ffrag c = {buv[ni], buv[ni], buv[ni], buv[ni]};
#pragma unroll
            for (int ki = 0; ki < 4; ++ki)
                c = __builtin_amdgcn_mfma_f32_16x16x32_bf16(af[ki], bg[ni][ki], c, 0, 0, 0);
            C[mi][ni] = c;
        }
    }
#pragma unroll
    for (int mi = 0; mi < 4; ++mi)
#pragma unroll
        for (int rr = 0; rr < 4; ++rr) {
            int nl = mi * 16 + q * 4 + rr;
            int gn = nb0 + nl;
            if (gn < N) {
#pragma unroll
                for (int ni = 0; ni < 4; ++ni) {
                    float hold = bf2f((unsigned short)xt[nl * 136 + ni * 16 + r]);
                    h[(size_t)gn * 64 + ni * 16 + r] =
                        fmaxf(C[mi][ni][rr], 0.f) + hold;
                }
            }
        }
}

// ---------------- fallback gather (tiny ws; R3 structure) ----------------
__global__ __launch_bounds__(256) void gather_msg_fallback(
        const float* __restrict__ Wm2, const float* __restrict__ We,
        const float* __restrict__ be, const void* __restrict__ ef,
        const int* __restrict__ srcs, const int* __restrict__ eid,
        const int* __restrict__ off, const float* __restrict__ A,
        float* __restrict__ agg, int N, const int* __restrict__ flagp) {
    int i = blockIdx.x * blockDim.x + threadIdx.x;
    if (i >= N) return;
    int isf32 = *flagp;
    int k0 = off[i], k1 = off[i + 1];
    float acc[64];
#pragma unroll
    for (int c = 0; c < 64; ++c) acc[c] = 0.f;
    for (int k = k0; k < k1; ++k) {
        int s = srcs[k];
        int e = eid[k];
        const float4* a4 = (const float4*)(A + (size_t)s * 64);
        float t[64];
#pragma unroll
        for (int c = 0; c < 16; ++c) {
            float4 v = a4[c];
            t[4 * c] = v.x; t[4 * c + 1] = v.y; t[4 * c + 2] = v.z; t[4 * c + 3] = v.w;
        }
        float efv[8];
        if (isf32) {
            const float4* e4 = (const float4*)ef + (size_t)e * 2;
            float4 ra = e4[0], rb = e4[1];
            efv[0]=ra.x; efv[1]=ra.y; efv[2]=ra.z; efv[3]=ra.w;
            efv[4]=rb.x; efv[5]=rb.y; efv[6]=rb.z; efv[7]=rb.w;
        } else {
            uint4 rr = ((const uint4*)ef)[e];
            efv[0]=bflo(rr.x); efv[1]=bfhi(rr.x); efv[2]=bflo(rr.y); efv[3]=bfhi(rr.y);
            efv[4]=bflo(rr.z); efv[5]=bfhi(rr.z); efv[6]=bflo(rr.w); efv[7]=bfhi(rr.w);
        }
#pragma unroll 1
        for (int d0 = 0; d0 < 64; d0 += 8) {
            float ev[8];
#pragma unroll
            for (int dd = 0; dd < 8; ++dd) {
                float a = be[d0 + dd];
#pragma unroll
                for (int kk = 0; kk < 8; ++kk) a = fmaf(efv[kk], We[kk * 64 + d0 + dd], a);
                ev[dd] = fmaxf(a, 0.f);
            }
#pragma unroll
            for (int dd = 0; dd < 8; ++dd) {
                const float* w = Wm2 + (d0 + dd) * 64;
#pragma unroll
                for (int c = 0; c < 64; ++c) t[c] = fmaf(ev[dd], w[c], t[c]);
            }
        }
#pragma unroll
        for (int c = 0; c < 64; ++c) acc[c] += fmaxf(t[c], 0.f);
    }
    float4* o4 = (float4*)(agg + (size_t)i * 64);
#pragma unroll
    for (int c = 0; c < 16; ++c)
        o4[c] = make_float4(acc[4 * c], acc[4 * c + 1], acc[4 * c + 2], acc[4 * c + 3]);
}

// ---------------- MFMA scores: out[p] = relu([h_s|h_d]@Ws1+bs1) . Ws2 + bs2 ----------------
// 2 waves/block, 64 pairs/wave; same K=128 structure as update. Ws2 dot done in
// C-register space + 16-lane shuffle reduction (no LDS round-trip).
__global__ __launch_bounds__(128) void scores_mfma_kernel(
        const short* __restrict__ Ws1T, const float* __restrict__ bs1,
        const float* __restrict__ Ws2, const float* __restrict__ bs2,
        const int* __restrict__ ods, const int* __restrict__ odd,
        const float* __restrict__ h, void* __restrict__ out, int P,
        const int* __restrict__ flagp) {
    __shared__ short lds_w[64 * 136];
    __shared__ short lds_x[2][64 * 136];
    const int tid = threadIdx.x, wid = tid >> 6, lane = tid & 63;
    const int r = lane & 15, q = lane >> 4;
    const int pb0 = blockIdx.x * 128 + wid * 64;
#pragma unroll
    for (int j = 0; j < 8; ++j) {
        int f8 = (tid * 8 + j) * 8;
        int row = f8 >> 7, k = f8 & 127;
        *(uint4*)&lds_w[row * 136 + k] = ((const uint4*)Ws1T)[tid * 8 + j];
    }
    short* xt = &lds_x[wid][0];
#pragma unroll 1
    for (int it = 0; it < 32; ++it) {
        int f4 = it * 64 + lane;
        int pr = f4 >> 5, c4 = f4 & 31;
        int gp = pb0 + pr; if (gp >= P) gp = P - 1;
        int node = (c4 < 16) ? ods[gp] : odd[gp];
        int cc = (c4 < 16) ? c4 : (c4 - 16);
        float4 v = ((const float4*)h)[(size_t)node * 16 + cc];
        *(uint2*)&xt[pr * 136 + c4 * 4] =
            make_uint2(pack2bf(v.x, v.y), pack2bf(v.z, v.w));
    }
    __syncthreads();

    bfrag bg[4][4];
#pragma unroll
    for (int ni = 0; ni < 4; ++ni)
#pragma unroll
        for (int ki = 0; ki < 4; ++ki)
            bg[ni][ki] = *(const bfrag*)&lds_w[(ni * 16 + r) * 136 + ki * 32 + q * 8];
    float buv[4], w2v[4];
#pragma unroll
    for (int ni = 0; ni < 4; ++ni) { buv[ni] = bs1[ni * 16 + r]; w2v[ni] = Ws2[ni * 16 + r]; }
    int isf32 = *flagp;
    float b2 = bs2[0];

#pragma unroll
    for (int mi = 0; mi < 4; ++mi) {
        bfrag af[4];
#pragma unroll
        for (int ki = 0; ki < 4; ++ki)
            af[ki] = *(const bfrag*)&xt[(mi * 16 + r) * 136 + ki * 32 + q * 8];
        float part[4] = {0.f, 0.f, 0.f, 0.f};
#pragma unroll
        for (int ni = 0; ni < 4; ++ni) {
            ffrag c = {buv[ni], buv[ni], buv[ni], buv[ni]};
#pragma unroll
            for (int ki = 0; ki < 4; ++ki)
                c = __builtin_amdgcn_mfma_f32_16x16x32_bf16(af[ki], bg[ni][ki], c, 0, 0, 0);
#pragma unroll
            for (int rr = 0; rr < 4; ++rr)
                part[rr] = fmaf(fmaxf(c[rr], 0.f), w2v[ni], part[rr]);
        }
        // sum over the 16 lanes sharing q (channel residues r=0..15)
#pragma unroll
        for (int rr = 0; rr < 4; ++rr) {
            float v = part[rr];
            v += __shfl_xor(v, 1); v += __shfl_xor(v, 2);
            v += __shfl_xor(v, 4); v += __shfl_xor(v, 8);
            if (r == 0) {
                int p = pb0 + mi * 16 + q * 4 + rr;
                if (p < P) {
                    float score = v + b2;
                    if (isf32) ((float*)out)[p] = score;
                    else ((__hip_bfloat16*)out)[p] = __float2bfloat16(score);
                }
            }
        }
    }
}

// ---------------- graph embed ----------------
__global__ __launch_bounds__(256) void embed_kernel(
        const float* __restrict__ h, float* __restrict__ gsum, int N) {
    __shared__ float red[256];
    int c = threadIdx.x & 63;
    int sub = threadIdx.x >> 6;   // 0..3
    float a = 0.f;
    for (int i = blockIdx.x * 4 + sub; i < N; i += gridDim.x * 4)
        a += h[(size_t)i * 64 + c];
    red[threadIdx.x] = a;
    __syncthreads();
    if (threadIdx.x < 64) {
        float t = red[threadIdx.x] + red[threadIdx.x + 64] +
                  red[threadIdx.x + 128] + red[threadIdx.x + 192];
        unsafeAtomicAdd(&gsum[threadIdx.x], t);
    }
}

// ---------------- dynamic-K head ----------------
__global__ void khead_kernel(const float* __restrict__ ws,
                             void* __restrict__ out, int N, int P,
                             const int* __restrict__ flagp) {
    if (threadIdx.x != 0 || blockIdx.x != 0) return;
    float x[68];
    float invN = 1.f / (float)N;
#pragma unroll
    for (int c = 0; c < 64; ++c) x[c] = ws[OFF_GSUM + c] * invN;
#pragma unroll
    for (int k = 0; k < 4; ++k) x[64 + k] = ws[OFF_TS + k];
    float h1[32];
    for (int j = 0; j < 32; ++j) {
        float a = ws[OFF_BK1 + j];
        for (int i = 0; i < 68; ++i) a = fmaf(x[i], ws[OFF_WK1 + i * 32 + j], a);
        h1[j] = fmaxf(a, 0.f);
    }
    float h2[16];
    for (int k2 = 0; k2 < 16; ++k2) {
        float a = ws[OFF_BK2 + k2];
        for (int j = 0; j < 32; ++j) a = fmaf(h1[j], ws[OFF_WK2 + j * 16 + k2], a);
        h2[k2] = fmaxf(a, 0.f);
    }
    float raw = ws[OFF_BK3];
    for (int k2 = 0; k2 < 16; ++k2) raw = fmaf(h2[k2], ws[OFF_WK3 + k2], raw);
    float sig = 1.f / (1.f + expf(-raw));
    float k = 1.f + 49.f * sig;
    if (*flagp) ((float*)out)[P] = k;
    else ((__hip_bfloat16*)out)[P] = __float2bfloat16(k);
}

extern "C" void kernel_launch(void* const* d_in, const int* in_sizes, int n_in,
                              void* d_out, int out_size, void* d_ws, size_t ws_size,
                              hipStream_t stream) {
    const void* nf = d_in[0];
    const int*  ei = (const int*)d_in[1];
    const void* ef = d_in[2];
    const int*  od = (const int*)d_in[3];
    float* ws = (float*)d_ws;

    const int N = in_sizes[0] / 16;   // 50000
    const int E = in_sizes[1] / 2;    // 1200000
    const int P = in_sizes[3] / 2;    // 10000

    // layout: h, agg, A; deg/spans, off, cursor, pstart, eid, srcs, Wtrans; rec; pbuf
    float* h      = ws + OFF_H;
    float* agg    = h + (size_t)N * 64;
    float* A      = agg + (size_t)N * 64;
    int*   deg    = (int*)(A + (size_t)N * 64);   // N (reused as spans)
    int*   off    = deg + N;                      // N+1
    int*   cursor = off + N + 1;                  // N
    int*   pstart = cursor + N;                   // N+1
    int*   eid    = pstart + N + 1;               // E (fallback only)
    int*   srcs   = eid + E;                      // E (fallback only)
    short* WbT    = (short*)(srcs + E);           // 59392 shorts: WbT|W1T|WuT|WeT|Ws1T
    short* W1T    = WbT + 12288;
    short* WuT    = WbT + 24576;
    short* WeT    = WbT + 49152;
    short* Ws1T   = WbT + 51200;
    int*   flag   = (int*)(ws + OFF_FLAG);
    int*   bsum   = (int*)(ws + OFF_BSUM);
    int*   boff   = (int*)(ws + OFF_BOFF);

    size_t fsofar = (size_t)OFF_H + 3 * (size_t)N * 64
                  + (size_t)(N + (N + 1) + N + (N + 1) + E + E) + 29696;
    size_t recOff = (fsofar + 15) & ~(size_t)15;          // 64-B align records
    float* rec = ws + recOff;
    size_t pbufOff = recOff + (size_t)E * 16;
    float* pbuf = ws + pbufOff;
    long pbufRows = (long)N + E / 64 + 128;
    size_t needBytes = (pbufOff + (size_t)pbufRows * 64) * sizeof(float);
    const bool big = (ws_size >= needBytes);

    const int* srcv = ei;
    const int* dstv = ei + E;

    // 0. dtype detect
    detect_dtype_kernel<<<1, 64, 0, stream>>>((const unsigned short*)nf, flag);

    // 1. convert weights to f32 in ws; build transposed bf16 weights
    ConvArgs ca;
    const int srcidx[19] = {5, 6, 7, 8, 9, 10, 11, 12, 13, 14, 15, 16, 17, 18, 19, 20, 21, 22, 4};
    const int wsoff[19]  = {OFF_WN, OFF_BN, OFF_WE, OFF_BE, OFF_WM, OFF_BM, OFF_WU, OFF_BU,
                            OFF_WS1, OFF_BS1, OFF_WS2, OFF_BS2, OFF_WK1, OFF_BK1, OFF_WK2,
                            OFF_BK2, OFF_WK3, OFF_BK3, OFF_TS};
    int maxn = 0;
    for (int i = 0; i < 19; ++i) {
        ca.src[i] = d_in[srcidx[i]];
        ca.off[i] = wsoff[i];
        ca.n[i]   = in_sizes[srcidx[i]];
        if (ca.n[i] > maxn) maxn = ca.n[i];
    }
    dim3 cgrid((maxn + 255) / 256, 19);
    convert_all_kernel<<<cgrid, 256, 0, stream>>>(ca, ws, flag);
    wtrans_prep_kernel<<<232, 256, 0, stream>>>(ws, WbT);

    // 2. node projection
    node_proj_kernel<<<(N * 64 + 255) / 256, 256, 0, stream>>>(nf, ws, h, N, flag);

    // 3. build CSR by dst (once). fill writes 64-B records in big mode.
    hipMemsetAsync(deg, 0, (size_t)N * sizeof(int), stream);
    count_kernel<<<(E + 255) / 256, 256, 0, stream>>>(dstv, deg, E);
    int nb = (N + 255) / 256;
    scan_blocks_kernel<<<nb, 256, 0, stream>>>(deg, cursor, bsum, N);
    scan_bsum_kernel<<<1, 256, 0, stream>>>(bsum, boff, nb);
    scan_finalize_kernel<<<nb, 256, 0, stream>>>(deg, cursor, boff, off, cursor, N, E);
    fill_kernel<<<(E + 255) / 256, 256, 0, stream>>>(
        srcv, dstv, ef, cursor, eid, srcs, rec, E, big ? 1 : 0, flag);

    // 3b. pstart = exclusive scan of wave-span counts (big path only)
    if (big) {
        spans_kernel<<<nb, 256, 0, stream>>>(off, deg, N);       // deg := spans
        scan_blocks_kernel<<<nb, 256, 0, stream>>>(deg, cursor, bsum, N);
        scan_bsum_kernel<<<1, 256, 0, stream>>>(bsum, boff, nb);
        scan_finalize_kernel<<<nb, 256, 0, stream>>>(deg, cursor, boff, pstart, cursor, N, 0);
    }

    // 4. GNN layers (R10 structure: nodeA -> msg -> fixup -> update)
    const int N4 = N * 4;
    const int mblocks = (E + 255) / 256;
    const int ablocks = (N + 255) / 256;
    const int ublocks = (N + 127) / 128;
    for (int l = 0; l < 3; ++l) {
        nodeA_mfma_kernel<<<ablocks, 256, 0, stream>>>(
            W1T + l * 4096, ws + OFF_BM + l * 64, h, A, N);
        if (big) {
            msg_mfma_red<<<mblocks, 256, 0, stream>>>(
                WeT, ws + OFF_BE, WbT + l * 4096, rec, A, pbuf, off, pstart, E);
            fixup_kernel<<<(N4 + 255) / 256, 256, 0, stream>>>(
                pbuf, off, pstart, agg, N);
        } else {
            const float* Wm2 = ws + OFF_WM + l * 8192 + 4096;
            gather_msg_fallback<<<(N + 255) / 256, 256, 0, stream>>>(
                Wm2, ws + OFF_WE, ws + OFF_BE, ef, srcs, eid, off, A, agg, N, flag);
        }
        update_mfma_kernel<<<ublocks, 128, 0, stream>>>(
            WuT + l * 8192, ws + OFF_BU + l * 64, h, agg, N);
    }

    // 5. per-flow scores (MFMA)
    scores_mfma_kernel<<<(P + 127) / 128, 128, 0, stream>>>(
        Ws1T, ws + OFF_BS1, ws + OFF_WS2, ws + OFF_BS2,
        od, od + P, h, d_out, P, flag);

    // 6. graph embedding + dynamic-K head
    hipMemsetAsync(ws + OFF_GSUM, 0, 64 * sizeof(float), stream);
    embed_kernel<<<256, 256, 0, stream>>>(h, ws + OFF_GSUM, N);
    khead_kernel<<<1, 64, 0, stream>>>(ws, d_out, N, P, flag);
}